// Round 12
// baseline (134.725 us; speedup 1.0000x reference)
//
#include <hip/hip_runtime.h>

typedef unsigned int u32;
typedef unsigned short u16;
typedef __attribute__((ext_vector_type(8))) short bf16x8;
typedef __attribute__((ext_vector_type(4))) float f32x4;

#define T_TOK 12544   // 4*56*56
#define EMB   256
#define IMG   56
#define SCALE 0.17677669529663689f
#define HALO  196
#define KSTR  40      // sK row stride (u16)
#define VTSTR 208     // sVT row stride (u16)
#define PSTR  208     // sP row stride (u16)

__device__ __forceinline__ u32 bf16_rtne(float f) {
    u32 u = __builtin_bit_cast(u32, f);
    return (u + 0x7fffu + ((u >> 16) & 1u)) >> 16;
}
__device__ __forceinline__ float bf16_to_f(u32 h) { return __builtin_bit_cast(float, h << 16); }

// async global->LDS, 16B/lane; LDS dest must be wave-uniform base + lane*16
#define GLD16(g, l) __builtin_amdgcn_global_load_lds( \
    (const __attribute__((address_space(1))) u32*)(g), \
    (__attribute__((address_space(3))) u32*)(l), 16, 0, 0)

// b64 load -> bf16x8 with j=4..7 zeroed (K=16 tail inside a K=32 MFMA; the
// zero products are exact so the reduction stays bit-identical)
__device__ __forceinline__ bf16x8 half_frag(const u16* p) {
    const uint2 v = *(const uint2*)p;
    u32 tmp[4] = {v.x, v.y, 0u, 0u};
    return *(bf16x8*)tmp;
}

// ---------------------------------------------------------------------------
// Convert: x -> bf16, qkv weights -> bf16 stacked [768][256], wo -> hi/lo.
// ---------------------------------------------------------------------------
__global__ __launch_bounds__(256) void convert_kernel(
    const float* __restrict__ x, const float* __restrict__ wq, const float* __restrict__ wk,
    const float* __restrict__ wv, const float* __restrict__ wo,
    u16* __restrict__ xb, u16* __restrict__ bsh,
    u16* __restrict__ boh, u16* __restrict__ bol) {
    const int i = blockIdx.x * 256 + threadIdx.x;
    const int NX4 = T_TOK * EMB / 4;   // 802816
    if (i < NX4) {
        const float4 f = ((const float4*)x)[i];
        const float vf[4] = {f.x, f.y, f.z, f.w};
        ushort4 hv;
        u16* hp = (u16*)&hv;
        #pragma unroll
        for (int c = 0; c < 4; ++c) hp[c] = (u16)bf16_rtne(vf[c]);
        ((ushort4*)xb)[i] = hv;
    } else {
        const int j = i - NX4;                 // < 65536
        const int w = j >> 14, widx = j & 16383;
        const float* src = (w == 0) ? wq : (w == 1) ? wk : (w == 2) ? wv : wo;
        const float4 f = ((const float4*)src)[widx];
        const float vf[4] = {f.x, f.y, f.z, f.w};
        if (w < 3) {
            ushort4 hv;
            u16* hp = (u16*)&hv;
            #pragma unroll
            for (int c = 0; c < 4; ++c) hp[c] = (u16)bf16_rtne(vf[c]);
            ((ushort4*)bsh)[(w << 14) + widx] = hv;
        } else {
            ushort4 hv, lv;
            u16* hp = (u16*)&hv; u16* lp = (u16*)&lv;
            #pragma unroll
            for (int c = 0; c < 4; ++c) {
                const u32 h = bf16_rtne(vf[c]);
                hp[c] = (u16)h;
                lp[c] = (u16)bf16_rtne(vf[c] - bf16_to_f(h));
            }
            ((ushort4*)boh)[widx] = hv;
            ((ushort4*)bol)[widx] = lv;
        }
    }
}

// ---------------------------------------------------------------------------
// QKV GEMM, 64x64 tile (grid (12,196) = 2352 blocks ~ 8/CU vs the old 128-
// tile's 2.3/CU: same MFMA total, 4x the blocks for ramp/latency hiding).
// Single-pass bf16, GLD16 staging, double-buffered, one barrier per k-tile.
// Per-element K accumulation chain identical to r11 -> bit-identical.
// ---------------------------------------------------------------------------
__global__ __launch_bounds__(256) void qkv_mfma(
    const u16* __restrict__ xb, const u16* __restrict__ bsh,
    const float* __restrict__ bq, const float* __restrict__ bk, const float* __restrict__ bv,
    u16* __restrict__ qb, u16* __restrict__ kb, u16* __restrict__ vb) {
    __shared__ __attribute__((aligned(16))) u16 sA[2][64 * 32];   // 8 KB
    __shared__ __attribute__((aligned(16))) u16 sB[2][64 * 32];   // 8 KB
    const int nBase = blockIdx.x * 64;             // 0..767 (stacked qkv)
    const int mBase = blockIdx.y * 64;
    const int tid = threadIdx.x, wv = tid >> 6, ln = tid & 63;
    const int lrow = ln & 15, lqd = ln >> 4;
    const int rA = tid >> 2, kcA = tid & 3;
    const size_t gA = (size_t)(mBase + rA) * EMB + kcA * 8;
    const size_t gB = (size_t)(nBase + rA) * EMB + kcA * 8;
    const int lA = wv * 64 * 8;   // wave-uniform LDS base (chunk = tid)

    f32x4 acc[4];
    #pragma unroll
    for (int mi = 0; mi < 4; ++mi) acc[mi] = (f32x4){0.f, 0.f, 0.f, 0.f};

    GLD16(xb  + gA, &sA[0][lA]);
    GLD16(bsh + gB, &sB[0][lA]);

    for (int kt = 0; kt < 8; ++kt) {
        const int b = kt & 1;
        __syncthreads();
        if (kt < 7) {
            const int k0 = (kt + 1) * 32;
            GLD16(xb  + gA + k0, &sA[b ^ 1][lA]);
            GLD16(bsh + gB + k0, &sB[b ^ 1][lA]);
        }
        bf16x8 af[4];
        #pragma unroll
        for (int mi = 0; mi < 4; ++mi)
            af[mi] = *(const bf16x8*)&sA[b][(mi * 16 + lrow) * 32 + lqd * 8];
        const bf16x8 bf = *(const bf16x8*)&sB[b][(wv * 16 + lrow) * 32 + lqd * 8];
        #pragma unroll
        for (int mi = 0; mi < 4; ++mi)
            acc[mi] = __builtin_amdgcn_mfma_f32_16x16x32_bf16(af[mi], bf, acc[mi], 0, 0, 0);
    }

    const int which = nBase >> 8;   // 0=q, 1=k, 2=v (uniform per block)
    const float* bias = (which == 0) ? bq : (which == 1) ? bk : bv;
    u16* dst = (which == 0) ? qb : (which == 1) ? kb : vb;
    const int c = (nBase & 255) + wv * 16 + lrow;
    const float bz = bias[c];
    #pragma unroll
    for (int mi = 0; mi < 4; ++mi) {
        #pragma unroll
        for (int r = 0; r < 4; ++r) {
            const int row = mBase + mi * 16 + lqd * 4 + r;
            dst[(size_t)row * EMB + c] = (u16)bf16_rtne(acc[mi][r] + bz);
        }
    }
}

// ---------------------------------------------------------------------------
// Out-projection, 64x64 tile (784 blocks), 3-pass split-bf16, GLD16,
// double-buffered, one barrier per k-tile.
// ---------------------------------------------------------------------------
__global__ __launch_bounds__(256) void out_mfma(
    const u16* __restrict__ aoh, const u16* __restrict__ aol,
    const u16* __restrict__ boh, const u16* __restrict__ bol,
    const float* __restrict__ bo, float* __restrict__ out) {
    __shared__ __attribute__((aligned(16))) u16 sAh[2][64 * 32];
    __shared__ __attribute__((aligned(16))) u16 sAl[2][64 * 32];
    __shared__ __attribute__((aligned(16))) u16 sBh[2][64 * 32];
    __shared__ __attribute__((aligned(16))) u16 sBl[2][64 * 32];
    const int nBase = blockIdx.x * 64;
    const int mBase = blockIdx.y * 64;
    const int tid = threadIdx.x, wv = tid >> 6, ln = tid & 63;
    const int lrow = ln & 15, lqd = ln >> 4;
    const int rA = tid >> 2, kcA = tid & 3;
    const size_t gA = (size_t)(mBase + rA) * EMB + kcA * 8;
    const size_t gB = (size_t)(nBase + rA) * EMB + kcA * 8;
    const int lA = wv * 64 * 8;

    f32x4 acc[4];
    #pragma unroll
    for (int mi = 0; mi < 4; ++mi) acc[mi] = (f32x4){0.f, 0.f, 0.f, 0.f};

    GLD16(aoh + gA, &sAh[0][lA]);
    GLD16(aol + gA, &sAl[0][lA]);
    GLD16(boh + gB, &sBh[0][lA]);
    GLD16(bol + gB, &sBl[0][lA]);

    for (int kt = 0; kt < 8; ++kt) {
        const int b = kt & 1;
        __syncthreads();
        if (kt < 7) {
            const int k0 = (kt + 1) * 32;
            GLD16(aoh + gA + k0, &sAh[b ^ 1][lA]);
            GLD16(aol + gA + k0, &sAl[b ^ 1][lA]);
            GLD16(boh + gB + k0, &sBh[b ^ 1][lA]);
            GLD16(bol + gB + k0, &sBl[b ^ 1][lA]);
        }
        bf16x8 ah[4], al[4];
        #pragma unroll
        for (int mi = 0; mi < 4; ++mi) {
            ah[mi] = *(const bf16x8*)&sAh[b][(mi * 16 + lrow) * 32 + lqd * 8];
            al[mi] = *(const bf16x8*)&sAl[b][(mi * 16 + lrow) * 32 + lqd * 8];
        }
        const bf16x8 bh = *(const bf16x8*)&sBh[b][(wv * 16 + lrow) * 32 + lqd * 8];
        const bf16x8 bl = *(const bf16x8*)&sBl[b][(wv * 16 + lrow) * 32 + lqd * 8];
        #pragma unroll
        for (int mi = 0; mi < 4; ++mi) {
            acc[mi] = __builtin_amdgcn_mfma_f32_16x16x32_bf16(ah[mi], bh, acc[mi], 0, 0, 0);
            acc[mi] = __builtin_amdgcn_mfma_f32_16x16x32_bf16(al[mi], bh, acc[mi], 0, 0, 0);
            acc[mi] = __builtin_amdgcn_mfma_f32_16x16x32_bf16(ah[mi], bl, acc[mi], 0, 0, 0);
        }
    }

    const int ncol = nBase + wv * 16 + lrow;
    const float bz = bo[ncol];
    #pragma unroll
    for (int mi = 0; mi < 4; ++mi) {
        #pragma unroll
        for (int r = 0; r < 4; ++r) {
            const int row = mBase + mi * 16 + lqd * 4 + r;
            out[(size_t)row * EMB + ncol] = acc[mi][r] + bz;
        }
    }
}

// ---------------------------------------------------------------------------
// Attention (MFMA): 256 thr = 4 waves = one (img, 8x8 tile, head).
// LDS 39936 B -> 4 blocks/CU (was 44032 -> 3). All dead columns trimmed:
// VT/P strides 208, sK 208 rows; PV = 6 full K=32 steps + one K=32 step
// whose frags carry the 16 real k-values at j=0..3 and exact zeros at
// j=4..7 (bit-identical to multiplying the old zero-padded columns).
// ---------------------------------------------------------------------------
__global__ __launch_bounds__(256, 4) void attn_kernel(
    const u16* __restrict__ qb, const u16* __restrict__ kb, const u16* __restrict__ vb,
    u16* __restrict__ aoh, u16* __restrict__ aol) {
    __shared__ __attribute__((aligned(16))) u16 smem[19968];   // 39936 B
    u16* sVT = smem;            // [32][VTSTR=208]  V^T (persists)
    u16* sK  = smem + 6656;     // [208][KSTR=40]   K halo, rows>=196 zero
    u16* sP  = smem + 6656;     // [4][16][PSTR=208] overlays sK after barrier 2

    const int tid = threadIdx.x;
    const int w = tid >> 6, ln = tid & 63;
    const int lrow = ln & 15, lqd = ln >> 4;
    const int img = blockIdx.z >> 3, head = blockIdx.z & 7;
    const int ty0 = blockIdx.y * 8, tx0 = blockIdx.x * 8;

    // ---- stage K [p][d] (b128) and V transposed [d][p] (b16 scatter) ----
    // 1664 uint4-chunks: p 0..207 x c 0..3 x {K, V}
    for (int i = tid; i < 1664; i += 256) {
        const int mv = (i >= 832) ? 1 : 0;
        const int ii = i - 832 * mv;
        const int p = ii >> 2, c = ii & 3;
        const int pyh = p / 14, pxh = p - pyh * 14;
        const int gy = ty0 - 3 + pyh, gx = tx0 - 3 + pxh;
        const bool ok = (p < HALO) & ((unsigned)gy < 56u) & ((unsigned)gx < 56u);
        if (!mv) {
            u16* dstk = sK + p * KSTR + c * 8;
            if (ok) {
                const size_t tt = ((size_t)img * IMG + gy) * IMG + gx;
                *(uint4*)dstk = *(const uint4*)(kb + tt * EMB + head * 32 + c * 8);
            } else {
                *(uint4*)dstk = (uint4){0u, 0u, 0u, 0u};
            }
        } else {
            u16* dv = sVT + (c * 8) * VTSTR + p;
            if (ok) {
                const size_t tt = ((size_t)img * IMG + gy) * IMG + gx;
                const uint4 u = *(const uint4*)(vb + tt * EMB + head * 32 + c * 8);
                dv[0 * VTSTR] = (u16)(u.x & 0xffffu);
                dv[1 * VTSTR] = (u16)(u.x >> 16);
                dv[2 * VTSTR] = (u16)(u.y & 0xffffu);
                dv[3 * VTSTR] = (u16)(u.y >> 16);
                dv[4 * VTSTR] = (u16)(u.z & 0xffffu);
                dv[5 * VTSTR] = (u16)(u.z >> 16);
                dv[6 * VTSTR] = (u16)(u.w & 0xffffu);
                dv[7 * VTSTR] = (u16)(u.w >> 16);
            } else {
                #pragma unroll
                for (int j = 0; j < 8; ++j) dv[j * VTSTR] = 0;
            }
        }
    }

    // ---- Q A-fragment straight from global (bf16) ----
    const int mpix = w * 16 + lrow;
    const int qpy = mpix >> 3, qpx = mpix & 7;
    const size_t qtok = ((size_t)img * IMG + ty0 + qpy) * IMG + tx0 + qpx;
    const bf16x8 aq = *(const bf16x8*)&qb[qtok * EMB + head * 32 + lqd * 8];
    __syncthreads();

    // ---- QK: 13 N-tiles over halo 0..207 ----
    f32x4 ct[13];
    #pragma unroll
    for (int t = 0; t < 13; ++t) ct[t] = (f32x4){0.f, 0.f, 0.f, 0.f};
    #pragma unroll
    for (int t = 0; t < 13; ++t) {
        const bf16x8 bk = *(const bf16x8*)&sK[(t * 16 + lrow) * KSTR + lqd * 8];
        ct[t] = __builtin_amdgcn_mfma_f32_16x16x32_bf16(aq, bk, ct[t], 0, 0, 0);
    }

    // ---- mask + softmax in C layout (row = lqd*4+r, col = 16t+lrow) ----
    int pys[4], pxs[4];
    #pragma unroll
    for (int r = 0; r < 4; ++r) {
        const int row = lqd * 4 + r;
        pys[r] = 2 * w + (row >> 3);
        pxs[r] = row & 7;
    }
    float mr4[4] = {-1e30f, -1e30f, -1e30f, -1e30f};
    #pragma unroll
    for (int t = 0; t < 13; ++t) {
        const int col = t * 16 + lrow;
        const int hy = col / 14, hx = col - 14 * hy;
        const bool okc = (col < HALO);
        #pragma unroll
        for (int r = 0; r < 4; ++r) {
            const bool ok = ((unsigned)(hy - pys[r]) < 7u) &
                            ((unsigned)(hx - pxs[r]) < 7u) & okc;
            const float lv = ok ? ct[t][r] * SCALE : -1e30f;
            ct[t][r] = lv;
            mr4[r] = fmaxf(mr4[r], lv);
        }
    }
    #pragma unroll
    for (int r = 0; r < 4; ++r) {
        float m = mr4[r];
        m = fmaxf(m, __shfl_xor(m, 1));
        m = fmaxf(m, __shfl_xor(m, 2));
        m = fmaxf(m, __shfl_xor(m, 4));
        m = fmaxf(m, __shfl_xor(m, 8));
        mr4[r] = m;
    }
    float sr4[4] = {0.f, 0.f, 0.f, 0.f};
    #pragma unroll
    for (int t = 0; t < 13; ++t)
        #pragma unroll
        for (int r = 0; r < 4; ++r) {
            const float e = __expf(ct[t][r] - mr4[r]);
            ct[t][r] = e;
            sr4[r] += e;
        }
    #pragma unroll
    for (int r = 0; r < 4; ++r) {
        float s = sr4[r];
        s += __shfl_xor(s, 1);
        s += __shfl_xor(s, 2);
        s += __shfl_xor(s, 4);
        s += __shfl_xor(s, 8);
        sr4[r] = 1.0f / s;
    }

    __syncthreads();   // all QK reads of sK done; safe to overlay with P

    // ---- P (bf16) to LDS (rows are exactly 208 wide; no pad fill) ----
    u16* sPw = sP + w * 16 * PSTR;
    #pragma unroll
    for (int t = 0; t < 13; ++t)
        #pragma unroll
        for (int r = 0; r < 4; ++r)
            sPw[(lqd * 4 + r) * PSTR + t * 16 + lrow] = (u16)bf16_rtne(ct[t][r]);

    // ---- PV: O[16][32] = P[16x208] . VT[32x208]^T (6 full + 1 half step) --
    f32x4 o0 = (f32x4){0.f, 0.f, 0.f, 0.f};
    f32x4 o1 = (f32x4){0.f, 0.f, 0.f, 0.f};
    #pragma unroll
    for (int ks = 0; ks < 6; ++ks) {
        const bf16x8 ap  = *(const bf16x8*)&sPw[lrow * PSTR + ks * 32 + lqd * 8];
        const bf16x8 bv0 = *(const bf16x8*)&sVT[lrow * VTSTR + ks * 32 + lqd * 8];
        const bf16x8 bv1 = *(const bf16x8*)&sVT[(16 + lrow) * VTSTR + ks * 32 + lqd * 8];
        o0 = __builtin_amdgcn_mfma_f32_16x16x32_bf16(ap, bv0, o0, 0, 0, 0);
        o1 = __builtin_amdgcn_mfma_f32_16x16x32_bf16(ap, bv1, o1, 0, 0, 0);
    }
    {   // tail: k = 192..207 at j=0..3 per quad, zeros at j=4..7
        const bf16x8 ap  = half_frag(&sPw[lrow * PSTR + 192 + lqd * 4]);
        const bf16x8 bv0 = half_frag(&sVT[lrow * VTSTR + 192 + lqd * 4]);
        const bf16x8 bv1 = half_frag(&sVT[(16 + lrow) * VTSTR + 192 + lqd * 4]);
        o0 = __builtin_amdgcn_mfma_f32_16x16x32_bf16(ap, bv0, o0, 0, 0, 0);
        o1 = __builtin_amdgcn_mfma_f32_16x16x32_bf16(ap, bv1, o1, 0, 0, 0);
    }

    // ---- epilogue: scale by 1/s, split-bf16, store ----
    #pragma unroll
    for (int r = 0; r < 4; ++r) {
        const int row = lqd * 4 + r;
        const int opy = 2 * w + (row >> 3), opx = row & 7;
        const size_t ot = ((size_t)img * IMG + ty0 + opy) * IMG + tx0 + opx;
        const float inv = sr4[r];
        const float v0 = o0[r] * inv;
        const float v1 = o1[r] * inv;
        const size_t base = ot * EMB + head * 32;
        const u32 h0 = bf16_rtne(v0);
        aoh[base + lrow] = (u16)h0;
        aol[base + lrow] = (u16)bf16_rtne(v0 - bf16_to_f(h0));
        const u32 h1 = bf16_rtne(v1);
        aoh[base + 16 + lrow] = (u16)h1;
        aol[base + 16 + lrow] = (u16)bf16_rtne(v1 - bf16_to_f(h1));
    }
}

extern "C" void kernel_launch(void* const* d_in, const int* in_sizes, int n_in,
                              void* d_out, int out_size, void* d_ws, size_t ws_size,
                              hipStream_t stream) {
    const float* x  = (const float*)d_in[0];
    const float* wq = (const float*)d_in[1];
    const float* wk = (const float*)d_in[2];
    const float* wv = (const float*)d_in[3];
    const float* wo = (const float*)d_in[4];
    const float* bq = (const float*)d_in[5];
    const float* bk = (const float*)d_in[6];
    const float* bv = (const float*)d_in[7];
    const float* bo = (const float*)d_in[8];
    float* out = (float*)d_out;

    char* ws = (char*)d_ws;
    u16* xb  = (u16*)(ws);               // 6,422,528 B  bf16 x
    u16* qb  = (u16*)(ws +  6422528);    // 6,422,528 B
    u16* kb  = (u16*)(ws + 12845056);    // 6,422,528 B
    u16* vb  = (u16*)(ws + 19267584);    // 6,422,528 B
    u16* aoh = (u16*)(ws + 25690112);    // 6,422,528 B
    u16* aol = (u16*)(ws + 32112640);    // 6,422,528 B
    u16* bsh = (u16*)(ws + 38535168);    // 393,216 B  stacked qkv weights bf16
    u16* boh = (u16*)(ws + 38928384);    // 131,072 B  wo hi
    u16* bol = (u16*)(ws + 39059456);    // 131,072 B  wo lo -> 39,190,528 B

    convert_kernel<<<3392, 256, 0, stream>>>(x, wq, wk, wv, wo, xb, bsh, boh, bol);
    qkv_mfma<<<dim3(12, 196), 256, 0, stream>>>(xb, bsh, bq, bk, bv, qb, kb, vb);
    attn_kernel<<<dim3(7, 7, 32), 256, 0, stream>>>(qb, kb, vb, aoh, aol);
    out_mfma<<<dim3(4, 196), 256, 0, stream>>>(aoh, aol, boh, bol, bo, out);
}

// Round 13
// 130.944 us; speedup vs baseline: 1.0289x; 1.0289x over previous
//
#include <hip/hip_runtime.h>

typedef unsigned int u32;
typedef unsigned short u16;
typedef __attribute__((ext_vector_type(8))) short bf16x8;
typedef __attribute__((ext_vector_type(4))) float f32x4;

#define T_TOK 12544   // 4*56*56
#define EMB   256
#define IMG   56
#define SCALE 0.17677669529663689f
#define HALO  196
#define KSTR  40      // sK row stride (u16)
#define VTSTR 208     // sVT row stride (u16)
#define PSTR  136     // sP row stride (u16): 128-col window + 8 pad

__device__ __forceinline__ u32 bf16_rtne(float f) {
    u32 u = __builtin_bit_cast(u32, f);
    return (u + 0x7fffu + ((u >> 16) & 1u)) >> 16;
}
__device__ __forceinline__ float bf16_to_f(u32 h) { return __builtin_bit_cast(float, h << 16); }

// async global->LDS, 16B/lane; LDS dest must be wave-uniform base + lane*16
#define GLD16(g, l) __builtin_amdgcn_global_load_lds( \
    (const __attribute__((address_space(1))) u32*)(g), \
    (__attribute__((address_space(3))) u32*)(l), 16, 0, 0)

// ---------------------------------------------------------------------------
// Convert: x -> bf16, qkv weights -> bf16 stacked [768][256], wo -> hi/lo.
// ---------------------------------------------------------------------------
__global__ __launch_bounds__(256) void convert_kernel(
    const float* __restrict__ x, const float* __restrict__ wq, const float* __restrict__ wk,
    const float* __restrict__ wv, const float* __restrict__ wo,
    u16* __restrict__ xb, u16* __restrict__ bsh,
    u16* __restrict__ boh, u16* __restrict__ bol) {
    const int i = blockIdx.x * 256 + threadIdx.x;
    const int NX4 = T_TOK * EMB / 4;   // 802816
    if (i < NX4) {
        const float4 f = ((const float4*)x)[i];
        const float vf[4] = {f.x, f.y, f.z, f.w};
        ushort4 hv;
        u16* hp = (u16*)&hv;
        #pragma unroll
        for (int c = 0; c < 4; ++c) hp[c] = (u16)bf16_rtne(vf[c]);
        ((ushort4*)xb)[i] = hv;
    } else {
        const int j = i - NX4;                 // < 65536
        const int w = j >> 14, widx = j & 16383;
        const float* src = (w == 0) ? wq : (w == 1) ? wk : (w == 2) ? wv : wo;
        const float4 f = ((const float4*)src)[widx];
        const float vf[4] = {f.x, f.y, f.z, f.w};
        if (w < 3) {
            ushort4 hv;
            u16* hp = (u16*)&hv;
            #pragma unroll
            for (int c = 0; c < 4; ++c) hp[c] = (u16)bf16_rtne(vf[c]);
            ((ushort4*)bsh)[(w << 14) + widx] = hv;
        } else {
            ushort4 hv, lv;
            u16* hp = (u16*)&hv; u16* lp = (u16*)&lv;
            #pragma unroll
            for (int c = 0; c < 4; ++c) {
                const u32 h = bf16_rtne(vf[c]);
                hp[c] = (u16)h;
                lp[c] = (u16)bf16_rtne(vf[c] - bf16_to_f(h));
            }
            ((ushort4*)boh)[widx] = hv;
            ((ushort4*)bol)[widx] = lv;
        }
    }
}

// ---------------------------------------------------------------------------
// QKV GEMM, 64x64 tile (grid (12,196) = 2352 blocks), single-pass bf16,
// GLD16 staging, double-buffered, one barrier per k-tile.
// ---------------------------------------------------------------------------
__global__ __launch_bounds__(256) void qkv_mfma(
    const u16* __restrict__ xb, const u16* __restrict__ bsh,
    const float* __restrict__ bq, const float* __restrict__ bk, const float* __restrict__ bv,
    u16* __restrict__ qb, u16* __restrict__ kb, u16* __restrict__ vb) {
    __shared__ __attribute__((aligned(16))) u16 sA[2][64 * 32];
    __shared__ __attribute__((aligned(16))) u16 sB[2][64 * 32];
    const int nBase = blockIdx.x * 64;             // 0..767 (stacked qkv)
    const int mBase = blockIdx.y * 64;
    const int tid = threadIdx.x, wv = tid >> 6, ln = tid & 63;
    const int lrow = ln & 15, lqd = ln >> 4;
    const int rA = tid >> 2, kcA = tid & 3;
    const size_t gA = (size_t)(mBase + rA) * EMB + kcA * 8;
    const size_t gB = (size_t)(nBase + rA) * EMB + kcA * 8;
    const int lA = wv * 64 * 8;

    f32x4 acc[4];
    #pragma unroll
    for (int mi = 0; mi < 4; ++mi) acc[mi] = (f32x4){0.f, 0.f, 0.f, 0.f};

    GLD16(xb  + gA, &sA[0][lA]);
    GLD16(bsh + gB, &sB[0][lA]);

    for (int kt = 0; kt < 8; ++kt) {
        const int b = kt & 1;
        __syncthreads();
        if (kt < 7) {
            const int k0 = (kt + 1) * 32;
            GLD16(xb  + gA + k0, &sA[b ^ 1][lA]);
            GLD16(bsh + gB + k0, &sB[b ^ 1][lA]);
        }
        bf16x8 af[4];
        #pragma unroll
        for (int mi = 0; mi < 4; ++mi)
            af[mi] = *(const bf16x8*)&sA[b][(mi * 16 + lrow) * 32 + lqd * 8];
        const bf16x8 bf = *(const bf16x8*)&sB[b][(wv * 16 + lrow) * 32 + lqd * 8];
        #pragma unroll
        for (int mi = 0; mi < 4; ++mi)
            acc[mi] = __builtin_amdgcn_mfma_f32_16x16x32_bf16(af[mi], bf, acc[mi], 0, 0, 0);
    }

    const int which = nBase >> 8;   // 0=q, 1=k, 2=v (uniform per block)
    const float* bias = (which == 0) ? bq : (which == 1) ? bk : bv;
    u16* dst = (which == 0) ? qb : (which == 1) ? kb : vb;
    const int c = (nBase & 255) + wv * 16 + lrow;
    const float bz = bias[c];
    #pragma unroll
    for (int mi = 0; mi < 4; ++mi) {
        #pragma unroll
        for (int r = 0; r < 4; ++r) {
            const int row = mBase + mi * 16 + lqd * 4 + r;
            dst[(size_t)row * EMB + c] = (u16)bf16_rtne(acc[mi][r] + bz);
        }
    }
}

// ---------------------------------------------------------------------------
// Out-projection, 64x64 tile (784 blocks), 3-pass split-bf16, GLD16,
// double-buffered, one barrier per k-tile.
// ---------------------------------------------------------------------------
__global__ __launch_bounds__(256) void out_mfma(
    const u16* __restrict__ aoh, const u16* __restrict__ aol,
    const u16* __restrict__ boh, const u16* __restrict__ bol,
    const float* __restrict__ bo, float* __restrict__ out) {
    __shared__ __attribute__((aligned(16))) u16 sAh[2][64 * 32];
    __shared__ __attribute__((aligned(16))) u16 sAl[2][64 * 32];
    __shared__ __attribute__((aligned(16))) u16 sBh[2][64 * 32];
    __shared__ __attribute__((aligned(16))) u16 sBl[2][64 * 32];
    const int nBase = blockIdx.x * 64;
    const int mBase = blockIdx.y * 64;
    const int tid = threadIdx.x, wv = tid >> 6, ln = tid & 63;
    const int lrow = ln & 15, lqd = ln >> 4;
    const int rA = tid >> 2, kcA = tid & 3;
    const size_t gA = (size_t)(mBase + rA) * EMB + kcA * 8;
    const size_t gB = (size_t)(nBase + rA) * EMB + kcA * 8;
    const int lA = wv * 64 * 8;

    f32x4 acc[4];
    #pragma unroll
    for (int mi = 0; mi < 4; ++mi) acc[mi] = (f32x4){0.f, 0.f, 0.f, 0.f};

    GLD16(aoh + gA, &sAh[0][lA]);
    GLD16(aol + gA, &sAl[0][lA]);
    GLD16(boh + gB, &sBh[0][lA]);
    GLD16(bol + gB, &sBl[0][lA]);

    for (int kt = 0; kt < 8; ++kt) {
        const int b = kt & 1;
        __syncthreads();
        if (kt < 7) {
            const int k0 = (kt + 1) * 32;
            GLD16(aoh + gA + k0, &sAh[b ^ 1][lA]);
            GLD16(aol + gA + k0, &sAl[b ^ 1][lA]);
            GLD16(boh + gB + k0, &sBh[b ^ 1][lA]);
            GLD16(bol + gB + k0, &sBl[b ^ 1][lA]);
        }
        bf16x8 ah[4], al[4];
        #pragma unroll
        for (int mi = 0; mi < 4; ++mi) {
            ah[mi] = *(const bf16x8*)&sAh[b][(mi * 16 + lrow) * 32 + lqd * 8];
            al[mi] = *(const bf16x8*)&sAl[b][(mi * 16 + lrow) * 32 + lqd * 8];
        }
        const bf16x8 bh = *(const bf16x8*)&sBh[b][(wv * 16 + lrow) * 32 + lqd * 8];
        const bf16x8 bl = *(const bf16x8*)&sBl[b][(wv * 16 + lrow) * 32 + lqd * 8];
        #pragma unroll
        for (int mi = 0; mi < 4; ++mi) {
            acc[mi] = __builtin_amdgcn_mfma_f32_16x16x32_bf16(ah[mi], bh, acc[mi], 0, 0, 0);
            acc[mi] = __builtin_amdgcn_mfma_f32_16x16x32_bf16(al[mi], bh, acc[mi], 0, 0, 0);
            acc[mi] = __builtin_amdgcn_mfma_f32_16x16x32_bf16(ah[mi], bl, acc[mi], 0, 0, 0);
        }
    }

    const int ncol = nBase + wv * 16 + lrow;
    const float bz = bo[ncol];
    #pragma unroll
    for (int mi = 0; mi < 4; ++mi) {
        #pragma unroll
        for (int r = 0; r < 4; ++r) {
            const int row = mBase + mi * 16 + lqd * 4 + r;
            out[(size_t)row * EMB + ncol] = acc[mi][r] + bz;
        }
    }
}

// ---------------------------------------------------------------------------
// Attention (MFMA, windowed): 256 thr = 4 waves = one (img, 8x8 tile, head).
// Wave w's 16 pixels only attend within halo cols 28w..28w+111, so each wave
// runs QK/PV over an aligned 128-col window base8=(28w)&~7 ({0,24,56,80}):
// QK 13->8 MFMA, PV 14->8 MFMA (4 full K=32 steps, no tail), P stores 52->32.
// Masked cols produce P=exp(-1e30-m)=+0 exactly -> dropping the remaining
// zero columns only reorders exact-zero additions. LDS 30720 B -> 5 blk/CU.
// ---------------------------------------------------------------------------
__global__ __launch_bounds__(256, 5) void attn_kernel(
    const u16* __restrict__ qb, const u16* __restrict__ kb, const u16* __restrict__ vb,
    u16* __restrict__ aoh, u16* __restrict__ aol) {
    __shared__ __attribute__((aligned(16))) u16 smem[15360];   // 30720 B
    u16* sVT = smem;            // [32][VTSTR=208]  V^T (persists)
    u16* sK  = smem + 6656;     // [208][KSTR=40]   K halo, rows>=196 zero
    u16* sP  = smem + 6656;     // [4][16][PSTR=136] overlays sK after barrier 2

    const int tid = threadIdx.x;
    const int w = tid >> 6, ln = tid & 63;
    const int lrow = ln & 15, lqd = ln >> 4;
    const int img = blockIdx.z >> 3, head = blockIdx.z & 7;
    const int ty0 = blockIdx.y * 8, tx0 = blockIdx.x * 8;
    const int base8 = (28 * w) & ~7;   // {0, 24, 56, 80}

    // ---- stage K [p][d] (b128) and V transposed [d][p] (b16 scatter) ----
    for (int i = tid; i < 1664; i += 256) {
        const int mv = (i >= 832) ? 1 : 0;
        const int ii = i - 832 * mv;
        const int p = ii >> 2, c = ii & 3;
        const int pyh = p / 14, pxh = p - pyh * 14;
        const int gy = ty0 - 3 + pyh, gx = tx0 - 3 + pxh;
        const bool ok = (p < HALO) & ((unsigned)gy < 56u) & ((unsigned)gx < 56u);
        if (!mv) {
            u16* dstk = sK + p * KSTR + c * 8;
            if (ok) {
                const size_t tt = ((size_t)img * IMG + gy) * IMG + gx;
                *(uint4*)dstk = *(const uint4*)(kb + tt * EMB + head * 32 + c * 8);
            } else {
                *(uint4*)dstk = (uint4){0u, 0u, 0u, 0u};
            }
        } else {
            u16* dv = sVT + (c * 8) * VTSTR + p;
            if (ok) {
                const size_t tt = ((size_t)img * IMG + gy) * IMG + gx;
                const uint4 u = *(const uint4*)(vb + tt * EMB + head * 32 + c * 8);
                dv[0 * VTSTR] = (u16)(u.x & 0xffffu);
                dv[1 * VTSTR] = (u16)(u.x >> 16);
                dv[2 * VTSTR] = (u16)(u.y & 0xffffu);
                dv[3 * VTSTR] = (u16)(u.y >> 16);
                dv[4 * VTSTR] = (u16)(u.z & 0xffffu);
                dv[5 * VTSTR] = (u16)(u.z >> 16);
                dv[6 * VTSTR] = (u16)(u.w & 0xffffu);
                dv[7 * VTSTR] = (u16)(u.w >> 16);
            } else {
                #pragma unroll
                for (int j = 0; j < 8; ++j) dv[j * VTSTR] = 0;
            }
        }
    }

    // ---- Q A-fragment straight from global (bf16) ----
    const int mpix = w * 16 + lrow;
    const int qpy = mpix >> 3, qpx = mpix & 7;
    const size_t qtok = ((size_t)img * IMG + ty0 + qpy) * IMG + tx0 + qpx;
    const bf16x8 aq = *(const bf16x8*)&qb[qtok * EMB + head * 32 + lqd * 8];
    __syncthreads();

    // ---- QK: 8 N-tiles over this wave's window base8..base8+127 ----
    f32x4 ct[8];
    #pragma unroll
    for (int t = 0; t < 8; ++t) ct[t] = (f32x4){0.f, 0.f, 0.f, 0.f};
    #pragma unroll
    for (int t = 0; t < 8; ++t) {
        const bf16x8 bk = *(const bf16x8*)&sK[(base8 + t * 16 + lrow) * KSTR + lqd * 8];
        ct[t] = __builtin_amdgcn_mfma_f32_16x16x32_bf16(aq, bk, ct[t], 0, 0, 0);
    }

    // ---- mask + softmax in C layout (row = lqd*4+r, col = base8+16t+lrow) --
    int pys[4], pxs[4];
    #pragma unroll
    for (int r = 0; r < 4; ++r) {
        const int row = lqd * 4 + r;
        pys[r] = 2 * w + (row >> 3);
        pxs[r] = row & 7;
    }
    float mr4[4] = {-1e30f, -1e30f, -1e30f, -1e30f};
    #pragma unroll
    for (int t = 0; t < 8; ++t) {
        const int col = base8 + t * 16 + lrow;
        const int hy = col / 14, hx = col - 14 * hy;
        const bool okc = (col < HALO);
        #pragma unroll
        for (int r = 0; r < 4; ++r) {
            const bool ok = ((unsigned)(hy - pys[r]) < 7u) &
                            ((unsigned)(hx - pxs[r]) < 7u) & okc;
            const float lv = ok ? ct[t][r] * SCALE : -1e30f;
            ct[t][r] = lv;
            mr4[r] = fmaxf(mr4[r], lv);
        }
    }
    #pragma unroll
    for (int r = 0; r < 4; ++r) {
        float m = mr4[r];
        m = fmaxf(m, __shfl_xor(m, 1));
        m = fmaxf(m, __shfl_xor(m, 2));
        m = fmaxf(m, __shfl_xor(m, 4));
        m = fmaxf(m, __shfl_xor(m, 8));
        mr4[r] = m;
    }
    float sr4[4] = {0.f, 0.f, 0.f, 0.f};
    #pragma unroll
    for (int t = 0; t < 8; ++t)
        #pragma unroll
        for (int r = 0; r < 4; ++r) {
            const float e = __expf(ct[t][r] - mr4[r]);
            ct[t][r] = e;
            sr4[r] += e;
        }
    #pragma unroll
    for (int r = 0; r < 4; ++r) {
        float s = sr4[r];
        s += __shfl_xor(s, 1);
        s += __shfl_xor(s, 2);
        s += __shfl_xor(s, 4);
        s += __shfl_xor(s, 8);
        sr4[r] = 1.0f / s;
    }

    __syncthreads();   // all QK reads of sK done; safe to overlay with P

    // ---- P (bf16) to LDS: 8 tiles x 16 = the wave's 128-col window ----
    u16* sPw = sP + w * 16 * PSTR;
    #pragma unroll
    for (int t = 0; t < 8; ++t)
        #pragma unroll
        for (int r = 0; r < 4; ++r)
            sPw[(lqd * 4 + r) * PSTR + t * 16 + lrow] = (u16)bf16_rtne(ct[t][r]);

    // ---- PV: O[16][32] = P[16x128] . VT[32 rows, window cols]^T ----
    f32x4 o0 = (f32x4){0.f, 0.f, 0.f, 0.f};
    f32x4 o1 = (f32x4){0.f, 0.f, 0.f, 0.f};
    #pragma unroll
    for (int ks = 0; ks < 4; ++ks) {
        const bf16x8 ap  = *(const bf16x8*)&sPw[lrow * PSTR + ks * 32 + lqd * 8];
        const bf16x8 bv0 = *(const bf16x8*)&sVT[lrow * VTSTR + base8 + ks * 32 + lqd * 8];
        const bf16x8 bv1 = *(const bf16x8*)&sVT[(16 + lrow) * VTSTR + base8 + ks * 32 + lqd * 8];
        o0 = __builtin_amdgcn_mfma_f32_16x16x32_bf16(ap, bv0, o0, 0, 0, 0);
        o1 = __builtin_amdgcn_mfma_f32_16x16x32_bf16(ap, bv1, o1, 0, 0, 0);
    }

    // ---- epilogue: scale by 1/s, split-bf16, store ----
    #pragma unroll
    for (int r = 0; r < 4; ++r) {
        const int row = lqd * 4 + r;
        const int opy = 2 * w + (row >> 3), opx = row & 7;
        const size_t ot = ((size_t)img * IMG + ty0 + opy) * IMG + tx0 + opx;
        const float inv = sr4[r];
        const float v0 = o0[r] * inv;
        const float v1 = o1[r] * inv;
        const size_t base = ot * EMB + head * 32;
        const u32 h0 = bf16_rtne(v0);
        aoh[base + lrow] = (u16)h0;
        aol[base + lrow] = (u16)bf16_rtne(v0 - bf16_to_f(h0));
        const u32 h1 = bf16_rtne(v1);
        aoh[base + 16 + lrow] = (u16)h1;
        aol[base + 16 + lrow] = (u16)bf16_rtne(v1 - bf16_to_f(h1));
    }
}

extern "C" void kernel_launch(void* const* d_in, const int* in_sizes, int n_in,
                              void* d_out, int out_size, void* d_ws, size_t ws_size,
                              hipStream_t stream) {
    const float* x  = (const float*)d_in[0];
    const float* wq = (const float*)d_in[1];
    const float* wk = (const float*)d_in[2];
    const float* wv = (const float*)d_in[3];
    const float* wo = (const float*)d_in[4];
    const float* bq = (const float*)d_in[5];
    const float* bk = (const float*)d_in[6];
    const float* bv = (const float*)d_in[7];
    const float* bo = (const float*)d_in[8];
    float* out = (float*)d_out;

    char* ws = (char*)d_ws;
    u16* xb  = (u16*)(ws);               // 6,422,528 B  bf16 x
    u16* qb  = (u16*)(ws +  6422528);    // 6,422,528 B
    u16* kb  = (u16*)(ws + 12845056);    // 6,422,528 B
    u16* vb  = (u16*)(ws + 19267584);    // 6,422,528 B
    u16* aoh = (u16*)(ws + 25690112);    // 6,422,528 B
    u16* aol = (u16*)(ws + 32112640);    // 6,422,528 B
    u16* bsh = (u16*)(ws + 38535168);    // 393,216 B  stacked qkv weights bf16
    u16* boh = (u16*)(ws + 38928384);    // 131,072 B  wo hi
    u16* bol = (u16*)(ws + 39059456);    // 131,072 B  wo lo -> 39,190,528 B

    convert_kernel<<<3392, 256, 0, stream>>>(x, wq, wk, wv, wo, xb, bsh, boh, bol);
    qkv_mfma<<<dim3(12, 196), 256, 0, stream>>>(xb, bsh, bq, bk, bv, qb, kb, vb);
    attn_kernel<<<dim3(7, 7, 32), 256, 0, stream>>>(qb, kb, vb, aoh, aol);
    out_mfma<<<dim3(4, 196), 256, 0, stream>>>(aoh, aol, boh, bol, bo, out);
}